// Round 2
// baseline (1018.303 us; speedup 1.0000x reference)
//
#include <hip/hip_runtime.h>
#include <stdint.h>

typedef unsigned short ushort_t;
typedef __attribute__((ext_vector_type(8))) short short8;   // 8 bf16 = 4 VGPRs
typedef __attribute__((ext_vector_type(4))) float f32x4;

__device__ __forceinline__ float bf2f(ushort_t h) {
    union { unsigned u; float f; } v; v.u = ((unsigned)h) << 16; return v.f;
}
__device__ __forceinline__ ushort_t f2bf(float x) {
    union { float f; unsigned u; } v; v.f = x;
    unsigned r = v.u + 0x7fffu + ((v.u >> 16) & 1u);   // RNE
    return (ushort_t)(r >> 16);
}

__device__ __forceinline__ void gload_lds16(const ushort_t* g, ushort_t* l) {
    __builtin_amdgcn_global_load_lds(
        (const __attribute__((address_space(1))) void*)g,
        (__attribute__((address_space(3))) void*)l, 16, 0, 0);
}

// ---------------------------------------------------------------------------
// In-place hi/lo split of seq: fp32 row (2352) -> bf16 [hi(2352) | lo(2352)]
// One block per row; read-all -> barrier -> write-all (same bytes).
// Harness restores d_in from pristine before every launch, so mutation is OK.
// ---------------------------------------------------------------------------
__global__ void split_seq(float* __restrict__ seqf)
{
    const long m = blockIdx.x;
    const int t = threadIdx.x;
    float* row = seqf + m * 2352;
    ushort_t* orow = (ushort_t*)row;
    float vals[10];
#pragma unroll
    for (int i = 0; i < 10; ++i) {
        int c = t + i * 256;
        vals[i] = (c < 2352) ? row[c] : 0.f;
    }
    __syncthreads();
#pragma unroll
    for (int i = 0; i < 10; ++i) {
        int c = t + i * 256;
        if (c < 2352) {
            ushort_t hi = f2bf(vals[i]);
            ushort_t lo = f2bf(vals[i] - bf2f(hi));
            orow[c] = hi;
            orow[2352 + c] = lo;
        }
    }
}

// ---------------------------------------------------------------------------
// Weight prep: out[n*3K + s*K + k] = seg s of W^T, bf16.
//   kk = k - shift; value = W[kk][n] if 0<=kk<Ksrc else 0
//   s=0,1: hi(bf16 RNE of fp32 w); s=2: lo = bf16(w - f32(hi))
// ---------------------------------------------------------------------------
__global__ void prep_wt(const float* __restrict__ W, int Ksrc, int Nsrc,
                        ushort_t* __restrict__ out, int K, int shift, int total)
{
    int idx = blockIdx.x * 256 + threadIdx.x;
    if (idx >= total) return;
    int n = idx / (3 * K);
    int r = idx - n * (3 * K);
    int s = r / K;
    int k = r - s * K;
    int kk = k - shift;
    float w = (kk >= 0 && kk < Ksrc) ? W[(long)kk * Nsrc + n] : 0.f;
    ushort_t hi = f2bf(w);
    out[idx] = (s < 2) ? hi : f2bf(w - bf2f(hi));
}

// x_pos (4 fp32 cols) -> concat buffer hi/lo + zero the pad columns
__global__ void prep_cat_pos(const float* __restrict__ seqf, ushort_t* __restrict__ cat)
{
    long t = (long)blockIdx.x * 256 + threadIdx.x;  // M*64 threads
    long m = t >> 6; int c = (int)(t & 63);
    float x = (c < 4) ? seqf[m * 2352 + 2348 + c] : 0.f;
    ushort_t hi = f2bf(x);
    ushort_t lo = f2bf(x - bf2f(hi));
    cat[m * 640 + 256 + c] = hi;    // hi section cols [256,320)
    cat[m * 640 + 576 + c] = lo;    // lo section cols [576,640)
}

// ---------------------------------------------------------------------------
// gemm_bt: C[m][n] = act( sum_{s,k} A_s[m][k] * Bt[n][s*K+k] + bias[n] )
//   3 segments: s=0 A-hi, s=1 A-lo, s=2 A-hi (pairs with Bt segs hi|hi|lo)
//   => (ah+al)(bh+bl) minus al*bl (~2^-16), i.e. fp32-quality bf16 MFMA GEMM.
// A: bf16 at A + m*lda + aoff_s + k (aoff_hi for s=0,2; aoff_lo for s=1)
// Bt: N x 3K bf16 row-major. K % 64 == 0.
// EPI 0: relu -> bf16 hi at outb[m*ostride+hi_off+n], lo at +lo_off
// EPI 1: tanh -> fp32 at outf[m*ostride+n]
// 128x128 tile, BK=64, 4 waves, XOR LDS swizzle, global_load_lds width16 (m97).
// ---------------------------------------------------------------------------
template<int EPI>
__global__ __launch_bounds__(256, 2)
void gemm_bt(const ushort_t* __restrict__ A, long lda, long aoff_hi, long aoff_lo,
             unsigned long long a_max,
             const ushort_t* __restrict__ Bt, int K,
             const float* __restrict__ bias,
             ushort_t* __restrict__ outb, float* __restrict__ outf,
             int ostride, int hi_off, int lo_off)
{
    __shared__ __align__(16) ushort_t As[128 * 64];
    __shared__ __align__(16) ushort_t Bs[128 * 64];

    const int t  = threadIdx.x;
    const int w  = t >> 6, l = t & 63;
    const int wm = w >> 1, wn = w & 1;
    const long m0 = (long)blockIdx.y * 128;
    const int  n0 = blockIdx.x * 128;
    const long K3 = 3L * K;

    // staging: chunk c=w*4+i covers LDS rows [c*8,c*8+8); lane l -> row c*8+(l>>3),
    // LDS k-block (l&7) holds global k-block (l&7)^(row&7)  (XOR swizzle, gather side)
    const int lr = l >> 3;
    const int kbg = (l & 7) ^ lr;
    unsigned long long rowA[4]; long rowB[4];
#pragma unroll
    for (int i = 0; i < 4; ++i) {
        int c = w * 4 + i;
        rowA[i] = (unsigned long long)((m0 + c * 8 + lr) * lda + kbg * 8);
        rowB[i] = (long)(n0 + c * 8 + lr) * K3 + kbg * 8;
    }

    f32x4 acc[4][4];
#pragma unroll
    for (int i = 0; i < 4; ++i)
#pragma unroll
        for (int j = 0; j < 4; ++j) acc[i][j] = (f32x4){0.f, 0.f, 0.f, 0.f};

    const int col = l & 15, quad = l >> 4;

    for (int s = 0; s < 3; ++s) {
        const long aoff = (s == 1) ? aoff_lo : aoff_hi;
        const long boff = (long)s * K;
        for (int k0 = 0; k0 < K; k0 += 64) {
            __syncthreads();            // prev compute done before LDS overwrite
#pragma unroll
            for (int i = 0; i < 4; ++i) {
                unsigned long long ae = rowA[i] + (unsigned long long)(aoff + k0);
                if (ae > a_max) ae = a_max;   // tail overrun -> valid addr (x0 weight)
                gload_lds16(A + ae, &As[(w * 4 + i) * 512]);
                gload_lds16(Bt + rowB[i] + boff + k0, &Bs[(w * 4 + i) * 512]);
            }
            __syncthreads();            // drains vmcnt(0): staging visible
#pragma unroll
            for (int kk = 0; kk < 2; ++kk) {
                short8 a[4], b[4];
#pragma unroll
                for (int i = 0; i < 4; ++i) {
                    int m = wm * 64 + i * 16 + col;
                    int kbs = (kk * 4 + quad) ^ (m & 7);
                    a[i] = *(const short8*)&As[m * 64 + kbs * 8];
                }
#pragma unroll
                for (int j = 0; j < 4; ++j) {
                    int n = wn * 64 + j * 16 + col;
                    int kbs = (kk * 4 + quad) ^ (n & 7);
                    b[j] = *(const short8*)&Bs[n * 64 + kbs * 8];
                }
#pragma unroll
                for (int i = 0; i < 4; ++i)
#pragma unroll
                    for (int j = 0; j < 4; ++j)
                        acc[i][j] = __builtin_amdgcn_mfma_f32_16x16x32_bf16(a[i], b[j], acc[i][j], 0, 0, 0);
            }
        }
    }

    // epilogue: C/D map col=lane&15, row=quad*4+reg (m89-verified)
#pragma unroll
    for (int j = 0; j < 4; ++j) {
        int n = n0 + wn * 64 + j * 16 + col;
        float bv = bias[n];
#pragma unroll
        for (int i = 0; i < 4; ++i) {
#pragma unroll
            for (int r = 0; r < 4; ++r) {
                long m = m0 + wm * 64 + i * 16 + quad * 4 + r;
                float y = acc[i][j][r] + bv;
                if (EPI == 0) {
                    y = fmaxf(y, 0.f);
                    ushort_t hi = f2bf(y);
                    ushort_t lo = f2bf(y - bf2f(hi));    // hi/lo: fp32-quality downstream
                    outb[m * (long)ostride + hi_off + n] = hi;
                    outb[m * (long)ostride + lo_off + n] = lo;
                } else {
                    outf[m * (long)ostride + n] = tanhf(y);
                }
            }
        }
    }
}

// ---------------------------------------------------------------------------
// Sinkhorn on scaling vectors: X = diag(u) K diag(v), K=exp(z*10) register-resident.
// col step: T_j = sum_i u_i K_ij ; v_j <- v_j/(eps + v_j T_j)  (== x/(eps+colsum))
// row step: R_i = sum_j K_ij v_j ; u_i <- u_i/(eps + u_i R_i)  (== x/(eps+rowsum))
// One block per batch; K held twice in regs (column- and row-distributed).
// ---------------------------------------------------------------------------
__global__ __launch_bounds__(256, 1)
void sinkhorn_k(const float* __restrict__ Z, float* __restrict__ out)
{
    __shared__ float P[256];
    __shared__ float u[128], v[128];
    const int t = threadIdx.x;
    const int jc = t & 127, h = t >> 7;
    const long base = (long)blockIdx.x * 16384;

    float Kc[64], Kr[64];
#pragma unroll
    for (int s = 0; s < 64; ++s)            // column copy: K[h+2s][jc], coalesced
        Kc[s] = __expf(Z[base + t + 256 * s] * 10.0f);
#pragma unroll
    for (int s = 0; s < 64; ++s)            // row copy: K[jc][h+2s]
        Kr[s] = __expf(Z[base + (long)jc * 128 + h + 2 * s] * 10.0f);

    if (t < 128) { u[t] = 1.f; v[t] = 1.f; }
    __syncthreads();

#pragma unroll 1
    for (int it = 0; it < 20; ++it) {
        float p = 0.f;
#pragma unroll
        for (int s = 0; s < 64; ++s) p += u[h + 2 * s] * Kc[s];
        P[t] = p;
        __syncthreads();
        if (t < 128) {
            float T = P[t] + P[t + 128];
            float vv = v[t];
            v[t] = vv / (1e-7f + vv * T);
        }
        __syncthreads();
        p = 0.f;
#pragma unroll
        for (int s = 0; s < 64; ++s) p += v[h + 2 * s] * Kr[s];
        P[t] = p;
        __syncthreads();
        if (t < 128) {
            float R = P[t] + P[t + 128];
            float uu = u[t];
            u[t] = uu / (1e-7f + uu * R);
        }
        __syncthreads();
    }

#pragma unroll
    for (int s = 0; s < 64; ++s)            // out[base + (h+2s)*128 + jc] == base+t+256s
        out[base + t + 256 * s] = u[h + 2 * s] * Kc[s] * v[jc];
}

// ---------------------------------------------------------------------------
extern "C" void kernel_launch(void* const* d_in, const int* in_sizes, int n_in,
                              void* d_out, int out_size, void* d_ws, size_t ws_size,
                              hipStream_t stream)
{
    float* seqf = (float*)d_in[0];               // mutated in place; harness restores
    const float* W1t = (const float*)d_in[1];
    const float* b1t = (const float*)d_in[2];
    const float* W1v = (const float*)d_in[3];
    const float* b1v = (const float*)d_in[4];
    const float* W2v = (const float*)d_in[5];
    const float* b2v = (const float*)d_in[6];
    const float* Wfp = (const float*)d_in[7];
    const float* bfp = (const float*)d_in[8];
    const float* Wfc = (const float*)d_in[9];
    const float* bfc = (const float*)d_in[10];

    char* ws = (char*)d_ws;
    size_t off = 0;
    auto alloc = [&](size_t bytes) { void* p = ws + off; off += (bytes + 255) & ~255ull; return p; };
    ushort_t* wt1 = (ushort_t*)alloc(128ull * 960 * 2);    // W1_txt^T  [h|h|l] K=320
    ushort_t* wt2 = (ushort_t*)alloc(512ull * 6336 * 2);   // W1_vis^T  [h|h|l] K=2112, shift12
    ushort_t* wt3 = (ushort_t*)alloc(128ull * 1536 * 2);   // W2_vis^T  [h|h|l] K=512
    ushort_t* wt4 = (ushort_t*)alloc(256ull * 960 * 2);    // W_fc_pos^T[h|h|l] K=320
    ushort_t* wt5 = (ushort_t*)alloc(128ull * 768 * 2);    // W_fc^T    [h|h|l] K=256
    ushort_t* vis = (ushort_t*)alloc(32768ull * 1024 * 2); // x_vis1 [hi(512)|lo(512)]
    ushort_t* cat = (ushort_t*)alloc(32768ull * 640 * 2);  // concat [hi(320)|lo(320)]
    ushort_t* fc  = (ushort_t*)alloc(32768ull * 512 * 2);  // fc_pos [hi(256)|lo(256)]
    float*    z   = (float*)alloc(32768ull * 128 * 4);     // tanh output fp32

    // pos must be read (fp32) BEFORE split_seq rewrites seq in place
    prep_cat_pos<<<8192, 256, 0, stream>>>(seqf, cat);
    split_seq<<<32768, 256, 0, stream>>>(seqf);

    auto prep = [&](const float* W, int Ksrc, int Nsrc, ushort_t* o, int K, int shift) {
        int total = Nsrc * 3 * K;
        prep_wt<<<(total + 255) / 256, 256, 0, stream>>>(W, Ksrc, Nsrc, o, K, shift, total);
    };
    prep(W1t, 300, 128, wt1, 320, 0);
    prep(W1v, 2048, 512, wt2, 2112, 12);   // seq hi col 288+k <-> W row k-12
    prep(W2v, 512, 128, wt3, 512, 0);
    prep(Wfp, 260, 256, wt4, 320, 0);
    prep(Wfc, 256, 128, wt5, 256, 0);

    const ushort_t* sequ = (const ushort_t*)seqf;   // [hi(2352)|lo(2352)] per row
    const unsigned long long seq_max = 32768ull * 4704 - 8;

    // GEMM1 (txt): K=320 (300 padded) -> cat cols [0,128) hi, [320,448) lo
    gemm_bt<0><<<dim3(1, 256), 256, 0, stream>>>(sequ, 4704, 0, 2352, seq_max,
                                                 wt1, 320, b1t, cat, nullptr, 640, 0, 320);
    // GEMM2 (vis1): 16B-aligned col 288, K=2112 (shift12 weights) -> vis hi|lo
    gemm_bt<0><<<dim3(4, 256), 256, 0, stream>>>(sequ, 4704, 288, 2640, seq_max,
                                                 wt2, 2112, b1v, vis, nullptr, 1024, 0, 512);
    // GEMM3 (vis2): A=vis, K=512 -> cat cols [128,256) hi, [448,576) lo
    gemm_bt<0><<<dim3(1, 256), 256, 0, stream>>>(vis, 1024, 0, 512, 32768ull * 1024 - 8,
                                                 wt3, 512, b2v, cat, nullptr, 640, 128, 448);
    // GEMM4 (fc_pos): A=cat, K=320 -> fc hi|lo
    gemm_bt<0><<<dim3(2, 256), 256, 0, stream>>>(cat, 640, 0, 320, 32768ull * 640 - 8,
                                                 wt4, 320, bfp, fc, nullptr, 512, 0, 256);
    // GEMM5 (fc): A=fc, K=256 -> z = tanh(.) fp32
    gemm_bt<1><<<dim3(1, 256), 256, 0, stream>>>(fc, 512, 0, 256, 32768ull * 512 - 8,
                                                 wt5, 256, bfc, nullptr, z, 128, 0, 0);

    sinkhorn_k<<<256, 256, 0, stream>>>(z, (float*)d_out);
}

// Round 3
// 881.347 us; speedup vs baseline: 1.1554x; 1.1554x over previous
//
#include <hip/hip_runtime.h>
#include <stdint.h>

typedef unsigned short ushort_t;
typedef __attribute__((ext_vector_type(8))) short short8;   // 8 bf16 = 4 VGPRs
typedef __attribute__((ext_vector_type(4))) float f32x4;

__device__ __forceinline__ float bf2f(ushort_t h) {
    union { unsigned u; float f; } v; v.u = ((unsigned)h) << 16; return v.f;
}
__device__ __forceinline__ ushort_t f2bf(float x) {
    union { float f; unsigned u; } v; v.f = x;
    unsigned r = v.u + 0x7fffu + ((v.u >> 16) & 1u);   // RNE
    return (ushort_t)(r >> 16);
}

__device__ __forceinline__ void gload_lds16(const ushort_t* g, ushort_t* l) {
    __builtin_amdgcn_global_load_lds(
        (const __attribute__((address_space(1))) void*)g,
        (__attribute__((address_space(3))) void*)l, 16, 0, 0);
}

// ---------------------------------------------------------------------------
// In-place hi/lo split of seq: fp32 row (2352) -> bf16 [hi(2352) | lo(2352)]
// Vectorized: float2 reads, packed ushort2 (uint) stores.
// Harness restores d_in from pristine before every launch, so mutation is OK.
// ---------------------------------------------------------------------------
__global__ void split_seq(float* __restrict__ seqf)
{
    const long m = blockIdx.x;
    const int t = threadIdx.x;
    float* row = seqf + m * 2352;
    float2 vals[5];
#pragma unroll
    for (int i = 0; i < 5; ++i) {
        int c2 = t + i * 256;                 // pair index, 1176 pairs
        vals[i] = (c2 < 1176) ? ((const float2*)row)[c2] : make_float2(0.f, 0.f);
    }
    __syncthreads();
    unsigned* orow = (unsigned*)row;          // row as 2352 uints? no: 1176+1176 packed
#pragma unroll
    for (int i = 0; i < 5; ++i) {
        int c2 = t + i * 256;
        if (c2 < 1176) {
            ushort_t h0 = f2bf(vals[i].x), h1 = f2bf(vals[i].y);
            ushort_t l0 = f2bf(vals[i].x - bf2f(h0));
            ushort_t l1 = f2bf(vals[i].y - bf2f(h1));
            orow[c2]        = (unsigned)h0 | ((unsigned)h1 << 16);   // hi section
            orow[1176 + c2] = (unsigned)l0 | ((unsigned)l1 << 16);   // lo section
        }
    }
}

// ---------------------------------------------------------------------------
// Weight prep: out[n*2K + s*K + k], s=0: bf16 hi of W^T, s=1: bf16 lo.
//   kk = k - shift; value = W[kk][n] if 0<=kk<Ksrc else 0
// ---------------------------------------------------------------------------
__global__ void prep_wt(const float* __restrict__ W, int Ksrc, int Nsrc,
                        ushort_t* __restrict__ out, int K, int shift, int total)
{
    int idx = blockIdx.x * 256 + threadIdx.x;
    if (idx >= total) return;
    int n = idx / (2 * K);
    int r = idx - n * (2 * K);
    int s = r / K;
    int k = r - s * K;
    int kk = k - shift;
    float w = (kk >= 0 && kk < Ksrc) ? W[(long)kk * Nsrc + n] : 0.f;
    ushort_t hi = f2bf(w);
    out[idx] = (s == 0) ? hi : f2bf(w - bf2f(hi));
}

// x_pos (4 fp32 cols) -> concat buffer hi/lo + zero the pad columns
__global__ void prep_cat_pos(const float* __restrict__ seqf, ushort_t* __restrict__ cat)
{
    long t = (long)blockIdx.x * 256 + threadIdx.x;  // M*64 threads
    long m = t >> 6; int c = (int)(t & 63);
    float x = (c < 4) ? seqf[m * 2352 + 2348 + c] : 0.f;
    ushort_t hi = f2bf(x);
    ushort_t lo = f2bf(x - bf2f(hi));
    cat[m * 640 + 256 + c] = hi;    // hi section cols [256,320)
    cat[m * 640 + 576 + c] = lo;    // lo section cols [576,640)
}

// ---------------------------------------------------------------------------
// gemm_bt: C[m][n] = act( A[m]·Bt[n] + bias[n] ) with fp32-quality bf16 MFMA:
//   3 passes per staged K-slab: Ah·Bh + Al·Bh + Ah·Bl  (drop Al·Bl ~2^-16)
// A: bf16, hi at A+m*lda+aoff_hi+k, lo at +aoff_lo. Bt: N x 2K [hi|lo] rows.
// 4 LDS buffers (64KB) staged ONCE per K-slab -> 96 MFMA per barrier pair.
// Grid: 1D, ntiles*mtiles blocks, XCD-swizzled so the ntiles N-tiles of an
// M-tile are congruent mod 8 (same XCD L2 -> A fetched ~once from HBM).
// EPI 0: relu -> bf16 hi/lo;  EPI 1: tanh -> fp32.
// ---------------------------------------------------------------------------
template<int EPI>
__global__ __launch_bounds__(256, 2)
void gemm_bt(const ushort_t* __restrict__ A, long lda, long aoff_hi, long aoff_lo,
             unsigned long long a_max,
             const ushort_t* __restrict__ Bt, int K, int ntiles,
             const float* __restrict__ bias,
             ushort_t* __restrict__ outb, float* __restrict__ outf,
             int ostride, int hi_off, int lo_off)
{
    __shared__ __align__(16) ushort_t Ah[128 * 64];
    __shared__ __align__(16) ushort_t Al[128 * 64];
    __shared__ __align__(16) ushort_t Bh[128 * 64];
    __shared__ __align__(16) ushort_t Bl[128 * 64];

    // XCD swizzle decode: lin = (by%8) + 8*(bx + ntiles*(by/8))
    const int b = blockIdx.x;
    const int tt = b >> 3;
    const int bx = tt % ntiles;
    const int by = (tt / ntiles) * 8 + (b & 7);

    const int t  = threadIdx.x;
    const int w  = t >> 6, l = t & 63;
    const int wm = w >> 1, wn = w & 1;
    const long m0 = (long)by * 128;
    const int  n0 = bx * 128;
    const long K2 = 2L * K;

    // staging: chunk c=w*4+i covers LDS rows [c*8,c*8+8); lane l -> row c*8+(l>>3),
    // LDS k-block (l&7) holds global k-block (l&7)^(row&7)  (XOR swizzle, gather side)
    const int lr = l >> 3;
    const int kbg = (l & 7) ^ lr;
    unsigned long long rowA[4]; long rowB[4];
#pragma unroll
    for (int i = 0; i < 4; ++i) {
        int c = w * 4 + i;
        rowA[i] = (unsigned long long)((m0 + c * 8 + lr) * lda + kbg * 8);
        rowB[i] = (long)(n0 + c * 8 + lr) * K2 + kbg * 8;
    }

    f32x4 acc[4][4];
#pragma unroll
    for (int i = 0; i < 4; ++i)
#pragma unroll
        for (int j = 0; j < 4; ++j) acc[i][j] = (f32x4){0.f, 0.f, 0.f, 0.f};

    const int col = l & 15, quad = l >> 4;

    for (int k0 = 0; k0 < K; k0 += 64) {
        __syncthreads();            // prev compute done before LDS overwrite
#pragma unroll
        for (int i = 0; i < 4; ++i) {
            const int cb = (w * 4 + i) * 512;
            unsigned long long ah = rowA[i] + (unsigned long long)(aoff_hi + k0);
            unsigned long long al = rowA[i] + (unsigned long long)(aoff_lo + k0);
            if (ah > a_max) ah = a_max;   // tail overrun -> valid addr (x0 weight)
            if (al > a_max) al = a_max;
            gload_lds16(A + ah, &Ah[cb]);
            gload_lds16(A + al, &Al[cb]);
            gload_lds16(Bt + rowB[i] + k0, &Bh[cb]);
            gload_lds16(Bt + rowB[i] + K + k0, &Bl[cb]);
        }
        __syncthreads();            // drains vmcnt(0): staging visible

#pragma unroll
        for (int p = 0; p < 3; ++p) {
            const ushort_t* Asrc = (p == 1) ? Al : Ah;
            const ushort_t* Bsrc = (p == 2) ? Bl : Bh;
#pragma unroll
            for (int kk = 0; kk < 2; ++kk) {
                short8 a[4], bb[4];
#pragma unroll
                for (int i = 0; i < 4; ++i) {
                    int m = wm * 64 + i * 16 + col;
                    int kbs = (kk * 4 + quad) ^ (m & 7);
                    a[i] = *(const short8*)&Asrc[m * 64 + kbs * 8];
                }
#pragma unroll
                for (int j = 0; j < 4; ++j) {
                    int n = wn * 64 + j * 16 + col;
                    int kbs = (kk * 4 + quad) ^ (n & 7);
                    bb[j] = *(const short8*)&Bsrc[n * 64 + kbs * 8];
                }
#pragma unroll
                for (int i = 0; i < 4; ++i)
#pragma unroll
                    for (int j = 0; j < 4; ++j)
                        acc[i][j] = __builtin_amdgcn_mfma_f32_16x16x32_bf16(a[i], bb[j], acc[i][j], 0, 0, 0);
            }
        }
    }

    // epilogue: C/D map col=lane&15, row=quad*4+reg (m89-verified)
#pragma unroll
    for (int j = 0; j < 4; ++j) {
        int n = n0 + wn * 64 + j * 16 + col;
        float bv = bias[n];
#pragma unroll
        for (int i = 0; i < 4; ++i) {
#pragma unroll
            for (int r = 0; r < 4; ++r) {
                long m = m0 + wm * 64 + i * 16 + quad * 4 + r;
                float y = acc[i][j][r] + bv;
                if (EPI == 0) {
                    y = fmaxf(y, 0.f);
                    ushort_t hi = f2bf(y);
                    ushort_t lo = f2bf(y - bf2f(hi));    // hi/lo: fp32-quality downstream
                    outb[m * (long)ostride + hi_off + n] = hi;
                    outb[m * (long)ostride + lo_off + n] = lo;
                } else {
                    outf[m * (long)ostride + n] = tanhf(y);
                }
            }
        }
    }
}

// ---------------------------------------------------------------------------
// Sinkhorn on scaling vectors: X = diag(u) K diag(v), K=exp(z*10) register-resident.
// col step: T_j = sum_i u_i K_ij ; v_j <- v_j/(eps + v_j T_j)  (== x/(eps+colsum))
// row step: R_i = sum_j K_ij v_j ; u_i <- u_i/(eps + u_i R_i)  (== x/(eps+rowsum))
// One block per batch; K held twice in regs (column- and row-distributed).
// ---------------------------------------------------------------------------
__global__ __launch_bounds__(256, 1)
void sinkhorn_k(const float* __restrict__ Z, float* __restrict__ out)
{
    __shared__ float P[256];
    __shared__ float u[128], v[128];
    const int t = threadIdx.x;
    const int jc = t & 127, h = t >> 7;
    const long base = (long)blockIdx.x * 16384;

    float Kc[64], Kr[64];
#pragma unroll
    for (int s = 0; s < 64; ++s)            // column copy: K[h+2s][jc], coalesced
        Kc[s] = __expf(Z[base + t + 256 * s] * 10.0f);
#pragma unroll
    for (int s = 0; s < 64; ++s)            // row copy: K[jc][h+2s]
        Kr[s] = __expf(Z[base + (long)jc * 128 + h + 2 * s] * 10.0f);

    if (t < 128) { u[t] = 1.f; v[t] = 1.f; }
    __syncthreads();

#pragma unroll 1
    for (int it = 0; it < 20; ++it) {
        float p = 0.f;
#pragma unroll
        for (int s = 0; s < 64; ++s) p += u[h + 2 * s] * Kc[s];
        P[t] = p;
        __syncthreads();
        if (t < 128) {
            float T = P[t] + P[t + 128];
            float vv = v[t];
            v[t] = vv / (1e-7f + vv * T);
        }
        __syncthreads();
        p = 0.f;
#pragma unroll
        for (int s = 0; s < 64; ++s) p += v[h + 2 * s] * Kr[s];
        P[t] = p;
        __syncthreads();
        if (t < 128) {
            float R = P[t] + P[t + 128];
            float uu = u[t];
            u[t] = uu / (1e-7f + uu * R);
        }
        __syncthreads();
    }

#pragma unroll
    for (int s = 0; s < 64; ++s)            // out[base + (h+2s)*128 + jc] == base+t+256s
        out[base + t + 256 * s] = u[h + 2 * s] * Kc[s] * v[jc];
}

// ---------------------------------------------------------------------------
extern "C" void kernel_launch(void* const* d_in, const int* in_sizes, int n_in,
                              void* d_out, int out_size, void* d_ws, size_t ws_size,
                              hipStream_t stream)
{
    float* seqf = (float*)d_in[0];               // mutated in place; harness restores
    const float* W1t = (const float*)d_in[1];
    const float* b1t = (const float*)d_in[2];
    const float* W1v = (const float*)d_in[3];
    const float* b1v = (const float*)d_in[4];
    const float* W2v = (const float*)d_in[5];
    const float* b2v = (const float*)d_in[6];
    const float* Wfp = (const float*)d_in[7];
    const float* bfp = (const float*)d_in[8];
    const float* Wfc = (const float*)d_in[9];
    const float* bfc = (const float*)d_in[10];

    char* ws = (char*)d_ws;
    size_t off = 0;
    auto alloc = [&](size_t bytes) { void* p = ws + off; off += (bytes + 255) & ~255ull; return p; };
    ushort_t* wt1 = (ushort_t*)alloc(128ull * 640 * 2);    // W1_txt^T  [h|l] K=320
    ushort_t* wt2 = (ushort_t*)alloc(512ull * 4224 * 2);   // W1_vis^T  [h|l] K=2112, shift12
    ushort_t* wt3 = (ushort_t*)alloc(128ull * 1024 * 2);   // W2_vis^T  [h|l] K=512
    ushort_t* wt4 = (ushort_t*)alloc(256ull * 640 * 2);    // W_fc_pos^T[h|l] K=320
    ushort_t* wt5 = (ushort_t*)alloc(128ull * 512 * 2);    // W_fc^T    [h|l] K=256
    ushort_t* vis = (ushort_t*)alloc(32768ull * 1024 * 2); // x_vis1 [hi(512)|lo(512)]
    ushort_t* cat = (ushort_t*)alloc(32768ull * 640 * 2);  // concat [hi(320)|lo(320)]
    ushort_t* fc  = (ushort_t*)alloc(32768ull * 512 * 2);  // fc_pos [hi(256)|lo(256)]
    float*    z   = (float*)alloc(32768ull * 128 * 4);     // tanh output fp32

    // pos must be read (fp32) BEFORE split_seq rewrites seq in place
    prep_cat_pos<<<8192, 256, 0, stream>>>(seqf, cat);
    split_seq<<<32768, 256, 0, stream>>>(seqf);

    auto prep = [&](const float* W, int Ksrc, int Nsrc, ushort_t* o, int K, int shift) {
        int total = Nsrc * 2 * K;
        prep_wt<<<(total + 255) / 256, 256, 0, stream>>>(W, Ksrc, Nsrc, o, K, shift, total);
    };
    prep(W1t, 300, 128, wt1, 320, 0);
    prep(W1v, 2048, 512, wt2, 2112, 12);   // seq hi col 288+k <-> W row k-12
    prep(W2v, 512, 128, wt3, 512, 0);
    prep(Wfp, 260, 256, wt4, 320, 0);
    prep(Wfc, 256, 128, wt5, 256, 0);

    const ushort_t* sequ = (const ushort_t*)seqf;   // [hi(2352)|lo(2352)] per row
    const unsigned long long seq_max = 32768ull * 4704 - 8;

    // GEMM1 (txt): K=320 (300 padded) -> cat cols [0,128) hi, [320,448) lo
    gemm_bt<0><<<256, 256, 0, stream>>>(sequ, 4704, 0, 2352, seq_max,
                                        wt1, 320, 1, b1t, cat, nullptr, 640, 0, 320);
    // GEMM2 (vis1): 16B-aligned col 288, K=2112 (shift12 weights) -> vis hi|lo
    gemm_bt<0><<<1024, 256, 0, stream>>>(sequ, 4704, 288, 2640, seq_max,
                                         wt2, 2112, 4, b1v, vis, nullptr, 1024, 0, 512);
    // GEMM3 (vis2): A=vis, K=512 -> cat cols [128,256) hi, [448,576) lo
    gemm_bt<0><<<256, 256, 0, stream>>>(vis, 1024, 0, 512, 32768ull * 1024 - 8,
                                        wt3, 512, 1, b2v, cat, nullptr, 640, 128, 448);
    // GEMM4 (fc_pos): A=cat, K=320 -> fc hi|lo
    gemm_bt<0><<<512, 256, 0, stream>>>(cat, 640, 0, 320, 32768ull * 640 - 8,
                                        wt4, 320, 2, bfp, fc, nullptr, 512, 0, 256);
    // GEMM5 (fc): A=fc, K=256 -> z = tanh(.) fp32
    gemm_bt<1><<<256, 256, 0, stream>>>(fc, 512, 0, 256, 32768ull * 512 - 8,
                                        wt5, 256, 1, bfc, nullptr, z, 128, 0, 0);

    sinkhorn_k<<<256, 256, 0, stream>>>(z, (float*)d_out);
}

// Round 4
// 725.307 us; speedup vs baseline: 1.4040x; 1.2151x over previous
//
#include <hip/hip_runtime.h>
#include <stdint.h>

typedef unsigned short ushort_t;
typedef __attribute__((ext_vector_type(8))) short short8;   // 8 bf16 = 4 VGPRs
typedef __attribute__((ext_vector_type(4))) float f32x4;
typedef __attribute__((ext_vector_type(4))) unsigned int u32x4;

__device__ __forceinline__ float bf2f(ushort_t h) {
    union { unsigned u; float f; } v; v.u = ((unsigned)h) << 16; return v.f;
}
__device__ __forceinline__ ushort_t f2bf(float x) {
    union { float f; unsigned u; } v; v.f = x;
    unsigned r = v.u + 0x7fffu + ((v.u >> 16) & 1u);   // RNE
    return (ushort_t)(r >> 16);
}

__device__ __forceinline__ void gload_lds16(const ushort_t* g, ushort_t* l) {
    __builtin_amdgcn_global_load_lds(
        (const __attribute__((address_space(1))) void*)g,
        (__attribute__((address_space(3))) void*)l, 16, 0, 0);
}

// ---------------------------------------------------------------------------
// Weight prep (coalesced tiled transpose, one read pass -> hi and lo):
//   out[n*2K + k]     = bf16_hi( W[k-shift][n] )   (0 if k-shift out of [0,Ksrc))
//   out[n*2K + K + k] = bf16_lo( " )
// 32x32 tile via LDS; reads coalesced over n, writes coalesced over k.
// ---------------------------------------------------------------------------
__global__ void prep_wt_t(const float* __restrict__ W, int Ksrc, int Nsrc,
                          ushort_t* __restrict__ out, int K, int shift)
{
    __shared__ float tile[32][33];
    const int kt = blockIdx.x * 32, nt = blockIdx.y * 32;
    const int tx = threadIdx.x & 31, ty = threadIdx.x >> 5;   // 32 x 8
#pragma unroll
    for (int r = ty; r < 32; r += 8) {
        int k = kt + r - shift;
        int n = nt + tx;
        tile[r][tx] = (k >= 0 && k < Ksrc && n < Nsrc) ? W[(long)k * Nsrc + n] : 0.f;
    }
    __syncthreads();
#pragma unroll
    for (int r = ty; r < 32; r += 8) {
        int n = nt + r, k = kt + tx;
        if (n < Nsrc && k < K) {
            float w = tile[tx][r];
            ushort_t hi = f2bf(w);
            out[(long)n * 2 * K + k]     = hi;
            out[(long)n * 2 * K + K + k] = f2bf(w - bf2f(hi));
        }
    }
}

// x_pos (4 fp32 cols of seq) -> concat buffer hi/lo + zero the pad columns
__global__ void prep_cat_pos(const float* __restrict__ seqf, ushort_t* __restrict__ cat)
{
    long t = (long)blockIdx.x * 256 + threadIdx.x;  // M*64 threads
    long m = t >> 6; int c = (int)(t & 63);
    float x = (c < 4) ? seqf[m * 2352 + 2348 + c] : 0.f;
    ushort_t hi = f2bf(x);
    ushort_t lo = f2bf(x - bf2f(hi));
    cat[m * 640 + 256 + c] = hi;    // hi section cols [256,320)
    cat[m * 640 + 576 + c] = lo;    // lo section cols [576,640)
}

// ===========================================================================
// Common GEMM pieces: 128x128 tile, BK=64, 4 waves, XOR LDS swizzle,
// 3 MFMA passes per staged slab (Ah·Bh + Al·Bh + Ah·Bl, drop Al·Bl ~2^-16).
// XCD swizzle: lin = (by%8) + 8*(bx + ntiles*(by/8)) -> N-tiles of one M-tile
// land on one XCD (shared L2 for the A window).
// ===========================================================================

// --- Variant A: A is fp32 (seq). Staging converts fp32 -> bf16 hi/lo in VGPRs,
//     ds_write_b128 with XOR swizzle on the write side. Relu epilogue.
__global__ __launch_bounds__(256, 2)
void gemm_af32(const float* __restrict__ Af, long ldaf, long aoff,
               unsigned long long a_maxf,        // clamp so [g, g+8) stays in-bounds
               const ushort_t* __restrict__ Bt, int K, int ntiles,
               const float* __restrict__ bias,
               ushort_t* __restrict__ outb, int ostride, int hi_off, int lo_off)
{
    __shared__ __align__(16) ushort_t Ah[128 * 64];
    __shared__ __align__(16) ushort_t Al[128 * 64];
    __shared__ __align__(16) ushort_t Bh[128 * 64];
    __shared__ __align__(16) ushort_t Bl[128 * 64];

    const int b = blockIdx.x;
    const int tt = b >> 3;
    const int bx = tt % ntiles;
    const int by = (tt / ntiles) * 8 + (b & 7);

    const int t  = threadIdx.x;
    const int w  = t >> 6, l = t & 63;
    const int wm = w >> 1, wn = w & 1;
    const long m0 = (long)by * 128;
    const int  n0 = bx * 128;
    const long K2 = 2L * K;

    // B staging (global_load_lds, gather-side XOR): chunk c=w*4+i, lane -> row c*8+(l>>3)
    const int lr = l >> 3;
    const int kbg = (l & 7) ^ lr;
    long rowB[4];
#pragma unroll
    for (int i = 0; i < 4; ++i) {
        int c = w * 4 + i;
        rowB[i] = (long)(n0 + c * 8 + lr) * K2 + kbg * 8;
    }

    // A staging cells: cell = i*256 + t -> r = cell>>3 (row), kb = cell&7 (k-block).
    // Lanes 0..7 cover one row's 8 k-blocks = 256B contiguous fp32 -> coalesced.
    unsigned long long agidx[4]; int lofs[4];
#pragma unroll
    for (int i = 0; i < 4; ++i) {
        int cell = i * 256 + t;
        int r = cell >> 3, kb = cell & 7;
        agidx[i] = (unsigned long long)((m0 + r) * ldaf + aoff + kb * 8);
        lofs[i] = r * 64 + ((kb ^ (r & 7)) * 8);   // XOR swizzle on write side
    }

    f32x4 acc[4][4];
#pragma unroll
    for (int i = 0; i < 4; ++i)
#pragma unroll
        for (int j = 0; j < 4; ++j) acc[i][j] = (f32x4){0.f, 0.f, 0.f, 0.f};

    const int col = l & 15, quad = l >> 4;

    for (int k0 = 0; k0 < K; k0 += 64) {
        __syncthreads();            // prev compute done before LDS overwrite
#pragma unroll
        for (int i = 0; i < 4; ++i) {
            const int cb = (w * 4 + i) * 512;
            gload_lds16(Bt + rowB[i] + k0, &Bh[cb]);       // async B while we convert A
            gload_lds16(Bt + rowB[i] + K + k0, &Bl[cb]);
        }
        float4 va[4][2];
#pragma unroll
        for (int i = 0; i < 4; ++i) {
            unsigned long long g = agidx[i] + (unsigned long long)k0;
            if (g > a_maxf) g = a_maxf;    // tail overrun -> valid addr (zero weights)
            va[i][0] = *(const float4*)(Af + g);
            va[i][1] = *(const float4*)(Af + g + 4);
        }
#pragma unroll
        for (int i = 0; i < 4; ++i) {
            float xs[8] = { va[i][0].x, va[i][0].y, va[i][0].z, va[i][0].w,
                            va[i][1].x, va[i][1].y, va[i][1].z, va[i][1].w };
            unsigned hp[4], lp[4];
#pragma unroll
            for (int p = 0; p < 4; ++p) {
                ushort_t h0 = f2bf(xs[2 * p]),     h1 = f2bf(xs[2 * p + 1]);
                ushort_t l0 = f2bf(xs[2 * p] - bf2f(h0));
                ushort_t l1 = f2bf(xs[2 * p + 1] - bf2f(h1));
                hp[p] = (unsigned)h0 | ((unsigned)h1 << 16);
                lp[p] = (unsigned)l0 | ((unsigned)l1 << 16);
            }
            *(u32x4*)&Ah[lofs[i]] = (u32x4){hp[0], hp[1], hp[2], hp[3]};
            *(u32x4*)&Al[lofs[i]] = (u32x4){lp[0], lp[1], lp[2], lp[3]};
        }
        __syncthreads();            // drains lgkm + vmcnt: staging visible

#pragma unroll
        for (int p = 0; p < 3; ++p) {
            const ushort_t* Asrc = (p == 1) ? Al : Ah;
            const ushort_t* Bsrc = (p == 2) ? Bl : Bh;
#pragma unroll
            for (int kk = 0; kk < 2; ++kk) {
                short8 a[4], bb[4];
#pragma unroll
                for (int i = 0; i < 4; ++i) {
                    int m = wm * 64 + i * 16 + col;
                    int kbs = (kk * 4 + quad) ^ (m & 7);
                    a[i] = *(const short8*)&Asrc[m * 64 + kbs * 8];
                }
#pragma unroll
                for (int j = 0; j < 4; ++j) {
                    int n = wn * 64 + j * 16 + col;
                    int kbs = (kk * 4 + quad) ^ (n & 7);
                    bb[j] = *(const short8*)&Bsrc[n * 64 + kbs * 8];
                }
#pragma unroll
                for (int i = 0; i < 4; ++i)
#pragma unroll
                    for (int j = 0; j < 4; ++j)
                        acc[i][j] = __builtin_amdgcn_mfma_f32_16x16x32_bf16(a[i], bb[j], acc[i][j], 0, 0, 0);
            }
        }
    }

    // epilogue: relu -> hi/lo bf16 (C/D map col=lane&15, row=quad*4+reg)
#pragma unroll
    for (int j = 0; j < 4; ++j) {
        int n = n0 + wn * 64 + j * 16 + col;
        float bv = bias[n];
#pragma unroll
        for (int i = 0; i < 4; ++i) {
#pragma unroll
            for (int r = 0; r < 4; ++r) {
                long m = m0 + wm * 64 + i * 16 + quad * 4 + r;
                float y = fmaxf(acc[i][j][r] + bv, 0.f);
                ushort_t hi = f2bf(y);
                ushort_t lo = f2bf(y - bf2f(hi));
                outb[m * (long)ostride + hi_off + n] = hi;
                outb[m * (long)ostride + lo_off + n] = lo;
            }
        }
    }
}

// --- Variant B: A is bf16 hi/lo (activations), global_load_lds staging. Relu.
__global__ __launch_bounds__(256, 2)
void gemm_bt(const ushort_t* __restrict__ A, long lda, long aoff_hi, long aoff_lo,
             unsigned long long a_max,
             const ushort_t* __restrict__ Bt, int K, int ntiles,
             const float* __restrict__ bias,
             ushort_t* __restrict__ outb, int ostride, int hi_off, int lo_off)
{
    __shared__ __align__(16) ushort_t Ah[128 * 64];
    __shared__ __align__(16) ushort_t Al[128 * 64];
    __shared__ __align__(16) ushort_t Bh[128 * 64];
    __shared__ __align__(16) ushort_t Bl[128 * 64];

    const int b = blockIdx.x;
    const int tt = b >> 3;
    const int bx = tt % ntiles;
    const int by = (tt / ntiles) * 8 + (b & 7);

    const int t  = threadIdx.x;
    const int w  = t >> 6, l = t & 63;
    const int wm = w >> 1, wn = w & 1;
    const long m0 = (long)by * 128;
    const int  n0 = bx * 128;
    const long K2 = 2L * K;

    const int lr = l >> 3;
    const int kbg = (l & 7) ^ lr;
    unsigned long long rowA[4]; long rowB[4];
#pragma unroll
    for (int i = 0; i < 4; ++i) {
        int c = w * 4 + i;
        rowA[i] = (unsigned long long)((m0 + c * 8 + lr) * lda + kbg * 8);
        rowB[i] = (long)(n0 + c * 8 + lr) * K2 + kbg * 8;
    }

    f32x4 acc[4][4];
#pragma unroll
    for (int i = 0; i < 4; ++i)
#pragma unroll
        for (int j = 0; j < 4; ++j) acc[i][j] = (f32x4){0.f, 0.f, 0.f, 0.f};

    const int col = l & 15, quad = l >> 4;

    for (int k0 = 0; k0 < K; k0 += 64) {
        __syncthreads();
#pragma unroll
        for (int i = 0; i < 4; ++i) {
            const int cb = (w * 4 + i) * 512;
            unsigned long long ah = rowA[i] + (unsigned long long)(aoff_hi + k0);
            unsigned long long al = rowA[i] + (unsigned long long)(aoff_lo + k0);
            if (ah > a_max) ah = a_max;
            if (al > a_max) al = a_max;
            gload_lds16(A + ah, &Ah[cb]);
            gload_lds16(A + al, &Al[cb]);
            gload_lds16(Bt + rowB[i] + k0, &Bh[cb]);
            gload_lds16(Bt + rowB[i] + K + k0, &Bl[cb]);
        }
        __syncthreads();

#pragma unroll
        for (int p = 0; p < 3; ++p) {
            const ushort_t* Asrc = (p == 1) ? Al : Ah;
            const ushort_t* Bsrc = (p == 2) ? Bl : Bh;
#pragma unroll
            for (int kk = 0; kk < 2; ++kk) {
                short8 a[4], bb[4];
#pragma unroll
                for (int i = 0; i < 4; ++i) {
                    int m = wm * 64 + i * 16 + col;
                    int kbs = (kk * 4 + quad) ^ (m & 7);
                    a[i] = *(const short8*)&Asrc[m * 64 + kbs * 8];
                }
#pragma unroll
                for (int j = 0; j < 4; ++j) {
                    int n = wn * 64 + j * 16 + col;
                    int kbs = (kk * 4 + quad) ^ (n & 7);
                    bb[j] = *(const short8*)&Bsrc[n * 64 + kbs * 8];
                }
#pragma unroll
                for (int i = 0; i < 4; ++i)
#pragma unroll
                    for (int j = 0; j < 4; ++j)
                        acc[i][j] = __builtin_amdgcn_mfma_f32_16x16x32_bf16(a[i], bb[j], acc[i][j], 0, 0, 0);
            }
        }
    }

#pragma unroll
    for (int j = 0; j < 4; ++j) {
        int n = n0 + wn * 64 + j * 16 + col;
        float bv = bias[n];
#pragma unroll
        for (int i = 0; i < 4; ++i) {
#pragma unroll
            for (int r = 0; r < 4; ++r) {
                long m = m0 + wm * 64 + i * 16 + quad * 4 + r;
                float y = fmaxf(acc[i][j][r] + bv, 0.f);
                ushort_t hi = f2bf(y);
                ushort_t lo = f2bf(y - bf2f(hi));
                outb[m * (long)ostride + hi_off + n] = hi;
                outb[m * (long)ostride + lo_off + n] = lo;
            }
        }
    }
}

// --- Variant C: GEMM5 + sinkhorn fused. One block = one 128x128 M-tile = one
// batch matrix. K-loop as variant B; epilogue writes tanh(z) into the dead
// staging LDS (swizzled col (n+m)&127 -> conflict-free row AND col reads),
// builds register K = exp(z*10), runs 20 sinkhorn iterations on u/v in LDS.
__global__ __launch_bounds__(256, 1)
void gemm_sink(const ushort_t* __restrict__ A, long lda, long aoff_hi, long aoff_lo,
               unsigned long long a_max,
               const ushort_t* __restrict__ Bt, int K,
               const float* __restrict__ bias,
               float* __restrict__ out)
{
    __shared__ __align__(16) unsigned char smem[65536];
    ushort_t* Ah = (ushort_t*)smem;              // 16 KB each
    ushort_t* Al = (ushort_t*)(smem + 16384);
    ushort_t* Bh = (ushort_t*)(smem + 32768);
    ushort_t* Bl = (ushort_t*)(smem + 49152);

    const int b = blockIdx.x;                    // batch index (identity swizzle)
    const int t  = threadIdx.x;
    const int w  = t >> 6, l = t & 63;
    const int wm = w >> 1, wn = w & 1;
    const long m0 = (long)b * 128;
    const long K2 = 2L * K;

    const int lr = l >> 3;
    const int kbg = (l & 7) ^ lr;
    unsigned long long rowA[4]; long rowB[4];
#pragma unroll
    for (int i = 0; i < 4; ++i) {
        int c = w * 4 + i;
        rowA[i] = (unsigned long long)((m0 + c * 8 + lr) * lda + kbg * 8);
        rowB[i] = (long)(c * 8 + lr) * K2 + kbg * 8;
    }

    f32x4 acc[4][4];
#pragma unroll
    for (int i = 0; i < 4; ++i)
#pragma unroll
        for (int j = 0; j < 4; ++j) acc[i][j] = (f32x4){0.f, 0.f, 0.f, 0.f};

    const int col = l & 15, quad = l >> 4;

    for (int k0 = 0; k0 < K; k0 += 64) {
        __syncthreads();
#pragma unroll
        for (int i = 0; i < 4; ++i) {
            const int cb = (w * 4 + i) * 512;
            unsigned long long ah = rowA[i] + (unsigned long long)(aoff_hi + k0);
            unsigned long long al = rowA[i] + (unsigned long long)(aoff_lo + k0);
            if (ah > a_max) ah = a_max;
            if (al > a_max) al = a_max;
            gload_lds16(A + ah, &Ah[cb]);
            gload_lds16(A + al, &Al[cb]);
            gload_lds16(Bt + rowB[i] + k0, &Bh[cb]);
            gload_lds16(Bt + rowB[i] + K + k0, &Bl[cb]);
        }
        __syncthreads();
#pragma unroll
        for (int p = 0; p < 3; ++p) {
            const ushort_t* Asrc = (p == 1) ? Al : Ah;
            const ushort_t* Bsrc = (p == 2) ? Bl : Bh;
#pragma unroll
            for (int kk = 0; kk < 2; ++kk) {
                short8 a[4], bb[4];
#pragma unroll
                for (int i = 0; i < 4; ++i) {
                    int m = wm * 64 + i * 16 + col;
                    int kbs = (kk * 4 + quad) ^ (m & 7);
                    a[i] = *(const short8*)&Asrc[m * 64 + kbs * 8];
                }
#pragma unroll
                for (int j = 0; j < 4; ++j) {
                    int n = wn * 64 + j * 16 + col;
                    int kbs = (kk * 4 + quad) ^ (n & 7);
                    bb[j] = *(const short8*)&Bsrc[n * 64 + kbs * 8];
                }
#pragma unroll
                for (int i = 0; i < 4; ++i)
#pragma unroll
                    for (int j = 0; j < 4; ++j)
                        acc[i][j] = __builtin_amdgcn_mfma_f32_16x16x32_bf16(a[i], bb[j], acc[i][j], 0, 0, 0);
            }
        }
    }

    // ---- epilogue: z = tanh(acc + bias) -> swizzled LDS ----
    __syncthreads();                       // LDS dead; reuse as z tile
    float* zs = (float*)smem;              // 128x128 fp32, col stored at (n+m)&127
#pragma unroll
    for (int j = 0; j < 4; ++j) {
        int n = wn * 64 + j * 16 + col;
        float bv = bias[n];
#pragma unroll
        for (int i = 0; i < 4; ++i) {
#pragma unroll
            for (int r = 0; r < 4; ++r) {
                int m = wm * 64 + i * 16 + quad * 4 + r;
                float y = acc[i][j][r] + bv;
                float e = __expf(2.f * y);             // tanh = 1 - 2/(e+1), inf-safe
                zs[m * 128 + ((n + m) & 127)] = 1.f - 2.f / (e + 1.f);
            }
        }
    }
    __syncthreads();

    // ---- sinkhorn: X = diag(u) K diag(v), K register-resident ----
    const int jc = t & 127, h = t >> 7;
    float Kc[64], Kr[64];
#pragma unroll
    for (int s = 0; s < 64; ++s) {         // column copy: K[h+2s][jc]
        int m = h + 2 * s;
        Kc[s] = __expf(zs[m * 128 + ((jc + m) & 127)] * 10.0f);
    }
#pragma unroll
    for (int s = 0; s < 64; ++s) {         // row copy: K[jc][h+2s]
        int n = h + 2 * s;
        Kr[s] = __expf(zs[jc * 128 + ((n + jc) & 127)] * 10.0f);
    }
    __syncthreads();                       // zs dead; carve u/v/P from smem
    float* P = (float*)smem;               // 256 floats
    float* u = P + 256;                    // 128
    float* v = u + 128;                    // 128
    if (t < 128) { u[t] = 1.f; v[t] = 1.f; }
    __syncthreads();

#pragma unroll 1
    for (int it = 0; it < 20; ++it) {
        float p = 0.f;
#pragma unroll
        for (int s = 0; s < 64; ++s) p += u[h + 2 * s] * Kc[s];
        P[t] = p;
        __syncthreads();
        if (t < 128) {
            float T = P[t] + P[t + 128];
            float vv = v[t];
            v[t] = vv / (1e-7f + vv * T);
        }
        __syncthreads();
        p = 0.f;
#pragma unroll
        for (int s = 0; s < 64; ++s) p += v[h + 2 * s] * Kr[s];
        P[t] = p;
        __syncthreads();
        if (t < 128) {
            float R = P[t] + P[t + 128];
            float uu = u[t];
            u[t] = uu / (1e-7f + uu * R);
        }
        __syncthreads();
    }

    const long base = m0 * 128;
#pragma unroll
    for (int s = 0; s < 64; ++s)           // out[(h+2s)*128 + jc] == t + 256s
        out[base + t + 256 * s] = u[h + 2 * s] * Kc[s] * v[jc];
}

// ---------------------------------------------------------------------------
extern "C" void kernel_launch(void* const* d_in, const int* in_sizes, int n_in,
                              void* d_out, int out_size, void* d_ws, size_t ws_size,
                              hipStream_t stream)
{
    const float* seqf = (const float*)d_in[0];
    const float* W1t = (const float*)d_in[1];
    const float* b1t = (const float*)d_in[2];
    const float* W1v = (const float*)d_in[3];
    const float* b1v = (const float*)d_in[4];
    const float* W2v = (const float*)d_in[5];
    const float* b2v = (const float*)d_in[6];
    const float* Wfp = (const float*)d_in[7];
    const float* bfp = (const float*)d_in[8];
    const float* Wfc = (const float*)d_in[9];
    const float* bfc = (const float*)d_in[10];

    char* ws = (char*)d_ws;
    size_t off = 0;
    auto alloc = [&](size_t bytes) { void* p = ws + off; off += (bytes + 255) & ~255ull; return p; };
    ushort_t* wt1 = (ushort_t*)alloc(128ull * 640 * 2);    // W1_txt^T  [h|l] K=320
    ushort_t* wt2 = (ushort_t*)alloc(512ull * 4224 * 2);   // W1_vis^T  [h|l] K=2112, shift12
    ushort_t* wt3 = (ushort_t*)alloc(128ull * 1024 * 2);   // W2_vis^T  [h|l] K=512
    ushort_t* wt4 = (ushort_t*)alloc(256ull * 640 * 2);    // W_fc_pos^T[h|l] K=320
    ushort_t* wt5 = (ushort_t*)alloc(128ull * 512 * 2);    // W_fc^T    [h|l] K=256
    ushort_t* vis = (ushort_t*)alloc(32768ull * 1024 * 2); // x_vis1 [hi(512)|lo(512)]
    ushort_t* cat = (ushort_t*)alloc(32768ull * 640 * 2);  // concat [hi(320)|lo(320)]
    ushort_t* fc  = (ushort_t*)alloc(32768ull * 512 * 2);  // fc_pos [hi(256)|lo(256)]

    auto prep = [&](const float* W, int Ksrc, int Nsrc, ushort_t* o, int K, int shift) {
        prep_wt_t<<<dim3((K + 31) / 32, (Nsrc + 31) / 32), 256, 0, stream>>>(W, Ksrc, Nsrc, o, K, shift);
    };
    prep(W1t, 300, 128, wt1, 320, 0);
    prep(W1v, 2048, 512, wt2, 2112, 12);   // seq col 288+k <-> W row k-12
    prep(W2v, 512, 128, wt3, 512, 0);
    prep(Wfp, 260, 256, wt4, 320, 0);
    prep(Wfc, 256, 128, wt5, 256, 0);
    prep_cat_pos<<<8192, 256, 0, stream>>>(seqf, cat);

    const unsigned long long seq_maxf = 32768ull * 2352 - 8;   // floats

    // GEMM1 (txt): fp32 seq cols [0,320), K=320 -> cat cols [0,128) hi, [320,448) lo
    gemm_af32<<<256, 256, 0, stream>>>(seqf, 2352, 0, seq_maxf,
                                       wt1, 320, 1, b1t, cat, 640, 0, 320);
    // GEMM2 (vis1): fp32 seq cols [288,2400), K=2112 (shift12 weights) -> vis hi|lo
    gemm_af32<<<1024, 256, 0, stream>>>(seqf, 2352, 288, seq_maxf,
                                        wt2, 2112, 4, b1v, vis, 1024, 0, 512);
    // GEMM3 (vis2): A=vis, K=512 -> cat cols [128,256) hi, [448,576) lo
    gemm_bt<<<256, 256, 0, stream>>>(vis, 1024, 0, 512, 32768ull * 1024 - 8,
                                     wt3, 512, 1, b2v, cat, 640, 128, 448);
    // GEMM4 (fc_pos): A=cat, K=320 -> fc hi|lo
    gemm_bt<<<512, 256, 0, stream>>>(cat, 640, 0, 320, 32768ull * 640 - 8,
                                     wt4, 320, 2, bfp, fc, 512, 0, 256);
    // GEMM5 + sinkhorn fused: A=fc, K=256 -> d_out
    gemm_sink<<<256, 256, 0, stream>>>(fc, 512, 0, 256, 32768ull * 512 - 8,
                                       wt5, 256, bfc, (float*)d_out);
}